// Round 8
// baseline (152.698 us; speedup 1.0000x reference)
//
#include <hip/hip_runtime.h>

#define T_SEQ 2048
#define C_DIM 1024
#define NH    16
#define NKV   4
#define HD    64
#define WIN   512

typedef __bf16 bf16x8 __attribute__((ext_vector_type(8)));
typedef float f32x4 __attribute__((ext_vector_type(4)));

#define MFMA16(a, b, c) __builtin_amdgcn_mfma_f32_16x16x32_bf16(a, b, c, 0, 0, 0)

__device__ __forceinline__ bf16x8 cvt8(uint4 u0, uint4 u1) {
  float4 a = *(float4*)&u0;
  float4 b = *(float4*)&u1;
  bf16x8 o;
  o[0] = (__bf16)a.x; o[1] = (__bf16)a.y; o[2] = (__bf16)a.z; o[3] = (__bf16)a.w;
  o[4] = (__bf16)b.x; o[5] = (__bf16)b.y; o[6] = (__bf16)b.z; o[7] = (__bf16)b.w;
  return o;
}

// chunk swizzle: spreads the 4 16B-chunks of each 64B LDS row so rows 4/8 apart
// hit different banks (rows 16 apart alias 2-way = free per m136)
__device__ __forceinline__ int swz(int row, int c) {
  return (c ^ (row & 3) ^ ((row >> 2) & 3)) & 3;
}

// ---------------- GEMM core: 128x64 tile, BK=32, depth-1 VGPR prefetch + LDS dbuf ----
// AF32: A is f32 (converted to bf16 during staging); else A is bf16. B always f32.
// All prefetch regs are individually named (R6 lesson: runtime-indexed local arrays
// lower to SCRATCH -> 66-133 MB spill traffic at VGPR_Count=68).
template <int AF32>
__device__ __forceinline__ void gemm_core32(const void* __restrict__ Av,
                                            const float* __restrict__ Bf,
                                            int K, int m0,
                                            __bf16* AsB, __bf16* BsB,
                                            f32x4 (&acc)[2][4]) {
  const int tid = threadIdx.x;
  const int w = tid >> 6, l = tid & 63;
  const int quad = l >> 4, r16 = l & 15;
  const int arow = tid >> 1;        // 0..127
  const int acol = (tid & 1) * 16;  // element offset in the 32-wide slab
  const int brow = tid >> 2;        // 0..63
  const int bcol = (tid & 3) * 8;
  const int wA0 = arow * 32 + swz(arow, (tid & 1) * 2) * 8;
  const int wA1 = arow * 32 + swz(arow, (tid & 1) * 2 + 1) * 8;
  const int wB0 = brow * 32 + swz(brow, tid & 3) * 8;
  int rA[2], rB[4];
#pragma unroll
  for (int mt = 0; mt < 2; ++mt) {
    int row = w * 32 + mt * 16 + r16;
    rA[mt] = row * 32 + swz(row, quad) * 8;
  }
#pragma unroll
  for (int nt = 0; nt < 4; ++nt) {
    int row = nt * 16 + r16;
    rB[nt] = row * 32 + swz(row, quad) * 8;
  }
  const float*  gAf = (const float*)Av + (size_t)(m0 + arow) * K + acol;
  const __bf16* gAh = (const __bf16*)Av + (size_t)(m0 + arow) * K + acol;
  const float*  gBf = Bf + (size_t)brow * K + bcol;

  const int nIter = K >> 5;  // 32
  uint4 a0, a1, a2, a3, b0, b1;  // named regs only (no arrays!)
  // prologue: slab 0
  if (AF32) {
    const uint4* p = (const uint4*)gAf;
    a0 = p[0]; a1 = p[1]; a2 = p[2]; a3 = p[3];
  } else {
    const uint4* p = (const uint4*)gAh;
    a0 = p[0]; a1 = p[1];
  }
  { const uint4* p = (const uint4*)gBf; b0 = p[0]; b1 = p[1]; }
  if (AF32) {
    bf16x8 c0 = cvt8(a0, a1), c1 = cvt8(a2, a3);
    *(bf16x8*)(AsB + wA0) = c0;
    *(bf16x8*)(AsB + wA1) = c1;
  } else {
    *(uint4*)(AsB + wA0) = a0;
    *(uint4*)(AsB + wA1) = a1;
  }
  *(bf16x8*)(BsB + wB0) = cvt8(b0, b1);
  __syncthreads();
  int cur = 0;
  for (int it = 0; it < nIter; ++it) {
    if (it + 1 < nIter) {  // prefetch next slab into named regs
      if (AF32) {
        const uint4* p = (const uint4*)(gAf + ((it + 1) << 5));
        a0 = p[0]; a1 = p[1]; a2 = p[2]; a3 = p[3];
      } else {
        const uint4* p = (const uint4*)(gAh + ((it + 1) << 5));
        a0 = p[0]; a1 = p[1];
      }
      const uint4* p = (const uint4*)(gBf + ((it + 1) << 5));
      b0 = p[0]; b1 = p[1];
    }
    const __bf16* Asc = AsB + cur * 4096;
    const __bf16* Bsc = BsB + cur * 2048;
    {
      bf16x8 fa0 = *(const bf16x8*)(Asc + rA[0]);
      bf16x8 fa1 = *(const bf16x8*)(Asc + rA[1]);
      bf16x8 fb0 = *(const bf16x8*)(Bsc + rB[0]);
      bf16x8 fb1 = *(const bf16x8*)(Bsc + rB[1]);
      bf16x8 fb2 = *(const bf16x8*)(Bsc + rB[2]);
      bf16x8 fb3 = *(const bf16x8*)(Bsc + rB[3]);
      acc[0][0] = MFMA16(fa0, fb0, acc[0][0]);
      acc[0][1] = MFMA16(fa0, fb1, acc[0][1]);
      acc[0][2] = MFMA16(fa0, fb2, acc[0][2]);
      acc[0][3] = MFMA16(fa0, fb3, acc[0][3]);
      acc[1][0] = MFMA16(fa1, fb0, acc[1][0]);
      acc[1][1] = MFMA16(fa1, fb1, acc[1][1]);
      acc[1][2] = MFMA16(fa1, fb2, acc[1][2]);
      acc[1][3] = MFMA16(fa1, fb3, acc[1][3]);
    }
    if (it + 1 < nIter) {
      __builtin_amdgcn_sched_barrier(0);  // keep prefetch+MFMA above the waiting writes
      __bf16* Asn = AsB + (cur ^ 1) * 4096;
      __bf16* Bsn = BsB + (cur ^ 1) * 2048;
      if (AF32) {
        bf16x8 c0 = cvt8(a0, a1), c1 = cvt8(a2, a3);
        *(bf16x8*)(Asn + wA0) = c0;
        *(bf16x8*)(Asn + wA1) = c1;
      } else {
        *(uint4*)(Asn + wA0) = a0;
        *(uint4*)(Asn + wA1) = a1;
      }
      *(bf16x8*)(Bsn + wB0) = cvt8(b0, b1);
      __syncthreads();
      cur ^= 1;
    }
  }
}

// ---------------- QKV GEMM (f32 in) + fused norm+RoPE (Q,K) / V-transpose epilogue ----
// grid (24,16): n0 = bx*64 in [0,1536). B source picked block-uniformly from Wq/Wkv.
__global__ __launch_bounds__(256) void gemm_qkv_kernel(const float* __restrict__ x,
                                                       const float* __restrict__ Wq,
                                                       const float* __restrict__ Wkv,
                                                       __bf16* __restrict__ Qb,
                                                       __bf16* __restrict__ Kb,
                                                       __bf16* __restrict__ Vt) {
  __shared__ __align__(16) __bf16 smem[12288];  // As 2x4096 | Bs 2x2048 (24 KB)
  __bf16* AsB = smem;
  __bf16* BsB = smem + 8192;
  f32x4 acc[2][4] = {};
  const int m0 = blockIdx.y * 128, n0 = blockIdx.x * 64;
  const float* Bsrc = (n0 < 1024) ? (Wq + (size_t)n0 * C_DIM)
                                  : (Wkv + (size_t)(n0 - 1024) * C_DIM);
  gemm_core32<1>(x, Bsrc, C_DIM, m0, AsB, BsB, acc);
  const int tid = threadIdx.x;
  const int w = tid >> 6, l = tid & 63, quad = l >> 4, r16 = l & 15;
  if (n0 < 1280) {  // Q or K: L2-norm + RoPE (cos/sin computed inline)
    const bool isQ = n0 < 1024;
    const int head = isQ ? (n0 >> 6) : ((n0 - 1024) >> 6);
    __bf16* dstBase = (isQ ? Qb : Kb) + (size_t)head * T_SEQ * HD;
    const float osc = isQ ? 0.125f : 1.0f;  // fold 1/sqrt(d) into Q (2^-3 exact)
    const float th0 = exp2f(-(float)r16 * (13.287712379549449f / 32.0f));
    const float th1 = exp2f(-(float)(16 + r16) * (13.287712379549449f / 32.0f));
#pragma unroll
    for (int mt = 0; mt < 2; ++mt) {
#pragma unroll
      for (int r = 0; r < 4; ++r) {
        float ss = acc[mt][0][r] * acc[mt][0][r] + acc[mt][1][r] * acc[mt][1][r] +
                   acc[mt][2][r] * acc[mt][2][r] + acc[mt][3][r] * acc[mt][3][r];
#pragma unroll
        for (int m = 1; m < 16; m <<= 1) ss += __shfl_xor(ss, m, 64);
        const float inv = osc / (sqrtf(ss) + 1e-6f);
        const int t = m0 + w * 32 + mt * 16 + quad * 4 + r;
        const float a0 = (float)t * th0, a1 = (float)t * th1;
        const float c0 = __cosf(a0), s0 = __sinf(a0);
        const float c1 = __cosf(a1), s1 = __sinf(a1);
        const float v0 = acc[mt][0][r] * inv, v1 = acc[mt][1][r] * inv;
        const float v2 = acc[mt][2][r] * inv, v3 = acc[mt][3][r] * inv;
        __bf16* dst = dstBase + (size_t)t * HD;
        dst[r16]      = (__bf16)(v0 * c0 - v2 * s0);
        dst[16 + r16] = (__bf16)(v1 * c1 - v3 * s1);
        dst[32 + r16] = (__bf16)(v2 * c0 + v0 * s0);
        dst[48 + r16] = (__bf16)(v3 * c1 + v1 * s1);
      }
    }
  } else {  // V: transpose to Vt[kvh][d][t] via reused LDS (needs 17.4 KB <= 24 KB)
    const int kvh = (n0 - 1280) >> 6;
    __syncthreads();  // all waves done reading As/Bs
    __bf16* Vs = smem;  // [64 d][stride 136]
#pragma unroll
    for (int mt = 0; mt < 2; ++mt)
#pragma unroll
      for (int nt = 0; nt < 4; ++nt)
#pragma unroll
        for (int r = 0; r < 4; ++r)
          Vs[(nt * 16 + r16) * 136 + w * 32 + mt * 16 + quad * 4 + r] = (__bf16)acc[mt][nt][r];
    __syncthreads();
    const int d = tid >> 2, tc = (tid & 3) * 32;
    __bf16* dst = Vt + ((size_t)kvh * HD + d) * T_SEQ + m0 + tc;
#pragma unroll
    for (int c2 = 0; c2 < 4; ++c2) {
      bf16x8 v = *(const bf16x8*)(Vs + d * 136 + tc + c2 * 8);
      *(bf16x8*)(dst + c2 * 8) = v;
    }
  }
}

// ---------------- proj GEMM: A=Yb bf16, B=Wproj f32, f32 epilogue ----------------
__global__ __launch_bounds__(256) void gemm_proj_kernel(const __bf16* __restrict__ Yb,
                                                        const float* __restrict__ Wp,
                                                        float* __restrict__ C) {
  __shared__ __align__(16) __bf16 smem[12288];
  __bf16* AsB = smem;
  __bf16* BsB = smem + 8192;
  f32x4 acc[2][4] = {};
  const int m0 = blockIdx.y * 128, n0 = blockIdx.x * 64;
  gemm_core32<0>(Yb, Wp + (size_t)n0 * C_DIM, C_DIM, m0, AsB, BsB, acc);
  const int tid = threadIdx.x;
  const int w = tid >> 6, l = tid & 63, quad = l >> 4, r16 = l & 15;
#pragma unroll
  for (int mt = 0; mt < 2; ++mt) {
    const int mrow = m0 + w * 32 + mt * 16 + quad * 4;
    const int ncol = n0 + r16;
#pragma unroll
    for (int r = 0; r < 4; ++r) {
      size_t rowoff = (size_t)(mrow + r) * C_DIM;
      C[rowoff + ncol]      = acc[mt][0][r];
      C[rowoff + ncol + 16] = acc[mt][1][r];
      C[rowoff + ncol + 32] = acc[mt][2][r];
      C[rowoff + ncol + 48] = acc[mt][3][r];
    }
  }
}

// ---------------- MFMA sliding-window attention: 16-q blocks, 4-way window split ----
// grid (T/16, NH) = 2048 blocks (8/CU). All 4 waves hold the same 16-query A-frags;
// wave w covers a quarter of the key chunks (per-wave chain ~2.2 chunks). Partials
// (O, lsum) combined through LDS -- valid without online-max since |s| <= 0.125.
// Pl (per-wave P staging) is OVERLAID on Oc, separated by a barrier, keeping LDS at
// ~17.7 KB so occupancy stays 8 blocks/CU (32 waves/CU).
__global__ __launch_bounds__(256) void attn_mfma_kernel(const __bf16* __restrict__ Qb,
                                                        const __bf16* __restrict__ Kb,
                                                        const __bf16* __restrict__ Vt,
                                                        __bf16* __restrict__ Yb) {
  __shared__ __align__(16) float Oc[4][16][68];  // 17408 B; also hosts Pl during the loop
  __shared__ float Ls[4][16];
  const int h = blockIdx.y, kvh = h >> 2;
  const int t0 = blockIdx.x * 16;
  const int tid = threadIdx.x;
  const int w = tid >> 6, l = tid & 63;
  const int quad = l >> 4, r16 = l & 15;
  __bf16* Plw = ((__bf16*)&Oc[0][0][0]) + w * 1152;  // per-wave [16][72]
  const __bf16* qptr = Qb + ((size_t)h * T_SEQ + t0 + r16) * HD + quad * 8;
  bf16x8 aq0 = *(const bf16x8*)(qptr);
  bf16x8 aq1 = *(const bf16x8*)(qptr + 32);
  const int keyStart = max(0, t0 - (WIN - 1)) & ~63;
  const int keyEnd = (t0 + 16 + 63) & ~63;
  const int nch = (keyEnd - keyStart) >> 6;  // <= 9
  const int cbeg = (w * nch) >> 2;
  const int cend = ((w + 1) * nch) >> 2;
  const __bf16* kbase = Kb + (size_t)kvh * T_SEQ * HD;
  const __bf16* vbase = Vt + (size_t)kvh * HD * T_SEQ;
  const int tq_base = t0 + quad * 4;
  f32x4 oacc[4] = {};
  float lsum[4] = {0.f, 0.f, 0.f, 0.f};
  for (int c = cbeg; c < cend; ++c) {
    const int key0 = keyStart + (c << 6);
    f32x4 s[4] = {};
#pragma unroll
    for (int nt = 0; nt < 4; ++nt) {
      const __bf16* kr = kbase + (size_t)(key0 + nt * 16 + r16) * HD + quad * 8;
      bf16x8 bk0 = *(const bf16x8*)kr;
      bf16x8 bk1 = *(const bf16x8*)(kr + 32);
      s[nt] = MFMA16(aq0, bk0, s[nt]);
      s[nt] = MFMA16(aq1, bk1, s[nt]);
    }
#pragma unroll
    for (int nt = 0; nt < 4; ++nt) {
      const int key = key0 + nt * 16 + r16;
#pragma unroll
      for (int r = 0; r < 4; ++r) {
        const int tq = tq_base + r;
        bool valid = (key <= tq) && (key > tq - WIN);
        float p = valid ? __expf(s[nt][r]) : 0.0f;
        lsum[r] += p;
        Plw[(quad * 4 + r) * 72 + nt * 16 + r16] = (__bf16)p;
      }
    }
    bf16x8 ap0 = *(const bf16x8*)(Plw + r16 * 72 + quad * 8);
    bf16x8 ap1 = *(const bf16x8*)(Plw + r16 * 72 + 32 + quad * 8);
#pragma unroll
    for (int nt = 0; nt < 4; ++nt) {
      const __bf16* vr = vbase + (size_t)(nt * 16 + r16) * T_SEQ + key0 + quad * 8;
      bf16x8 bv0 = *(const bf16x8*)vr;
      bf16x8 bv1 = *(const bf16x8*)(vr + 32);
      oacc[nt] = MFMA16(ap0, bv0, oacc[nt]);
      oacc[nt] = MFMA16(ap1, bv1, oacc[nt]);
    }
  }
  // reduce lsum across the 16 key-columns per quad group
#pragma unroll
  for (int r = 0; r < 4; ++r) {
#pragma unroll
    for (int m = 1; m < 16; m <<= 1) lsum[r] += __shfl_xor(lsum[r], m, 64);
  }
  __syncthreads();  // everyone done with Pl before Oc overwrites it
#pragma unroll
  for (int nt = 0; nt < 4; ++nt)
#pragma unroll
    for (int r = 0; r < 4; ++r)
      Oc[w][quad * 4 + r][nt * 16 + r16] = oacc[nt][r];
  if (r16 == 0) {
#pragma unroll
    for (int r = 0; r < 4; ++r) Ls[w][quad * 4 + r] = lsum[r];
  }
  __syncthreads();
  // combine 4 wave-partials: thread handles col=tid&63, rows (tid>>6)+4k
  {
    const int col = tid & 63;
    const int r0 = tid >> 6;
#pragma unroll
    for (int rr = 0; rr < 4; ++rr) {
      const int row = r0 + rr * 4;
      float o = Oc[0][row][col] + Oc[1][row][col] + Oc[2][row][col] + Oc[3][row][col];
      float dl = Ls[0][row] + Ls[1][row] + Ls[2][row] + Ls[3][row];
      Yb[(size_t)(t0 + row) * C_DIM + h * HD + col] = (__bf16)(o / dl);
    }
  }
}

extern "C" void kernel_launch(void* const* d_in, const int* in_sizes, int n_in,
                              void* d_out, int out_size, void* d_ws, size_t ws_size,
                              hipStream_t stream) {
  const float* x     = (const float*)d_in[0];
  const float* Wq    = (const float*)d_in[1];
  const float* Wkv   = (const float*)d_in[2];
  const float* Wproj = (const float*)d_in[3];
  float* out = (float*)d_out;

  __bf16* Qb = (__bf16*)d_ws;                    // [16][2048][64]
  __bf16* Kb = Qb + (size_t)NH * T_SEQ * HD;     // [4][2048][64]
  __bf16* Vt = Kb + (size_t)NKV * T_SEQ * HD;    // [4][64][2048]
  __bf16* Yb = Vt + (size_t)NKV * HD * T_SEQ;    // [2048][1024]

  gemm_qkv_kernel<<<dim3(24, 16), 256, 0, stream>>>(x, Wq, Wkv, Qb, Kb, Vt);
  attn_mfma_kernel<<<dim3(T_SEQ / 16, NH), 256, 0, stream>>>(Qb, Kb, Vt, Yb);
  gemm_proj_kernel<<<dim3(16, 16), 256, 0, stream>>>(Yb, Wproj, out);
}

// Round 9
// 132.264 us; speedup vs baseline: 1.1545x; 1.1545x over previous
//
#include <hip/hip_runtime.h>

#define T_SEQ 2048
#define C_DIM 1024
#define NH    16
#define NKV   4
#define HD    64
#define WIN   512

typedef __bf16 bf16x8 __attribute__((ext_vector_type(8)));
typedef __bf16 bf16x4 __attribute__((ext_vector_type(4)));
typedef float f32x4 __attribute__((ext_vector_type(4)));

#define MFMA16(a, b, c) __builtin_amdgcn_mfma_f32_16x16x32_bf16(a, b, c, 0, 0, 0)

// ---------------- prep: fused f32->bf16 casts + RoPE table (R7, proven) ----------------
__global__ __launch_bounds__(256) void prep_kernel(const float* __restrict__ x,
                                                   const float* __restrict__ Wq,
                                                   const float* __restrict__ Wkv,
                                                   const float* __restrict__ Wp,
                                                   __bf16* __restrict__ xb,
                                                   __bf16* __restrict__ Wqkvb,
                                                   __bf16* __restrict__ Wpb,
                                                   float2* __restrict__ ropeT) {
  int b = blockIdx.x;
  if (b >= 4608) {
    int idx = (b - 4608) * 256 + threadIdx.x;  // < 65536
    int t = idx >> 5, i = idx & 31;
    float theta = exp2f(-(float)i * (13.287712379549449f / 32.0f));
    float s, c;
    sincosf((float)t * theta, &s, &c);
    ropeT[idx] = make_float2(c, s);
    return;
  }
  const float* src;
  __bf16* dst;
  int off;
  if (b < 2048)      { src = x;   dst = xb;                off = b; }
  else if (b < 3072) { src = Wq;  dst = Wqkvb;             off = b - 2048; }
  else if (b < 3584) { src = Wkv; dst = Wqkvb + (1 << 20); off = b - 3072; }
  else               { src = Wp;  dst = Wpb;               off = b - 3584; }
  int i = off * 1024 + threadIdx.x * 4;
  float4 v = *(const float4*)(src + i);
  bf16x4 o;
  o[0] = (__bf16)v.x; o[1] = (__bf16)v.y; o[2] = (__bf16)v.z; o[3] = (__bf16)v.w;
  *(bf16x4*)(dst + i) = o;
}

// ---------------- GEMM core: 64x64 tile, BK=64, depth-1 named-reg prefetch + LDS dbuf ----
// R8 post-mortem: at 128x64 tiles the grids were 256-384 blocks = 1-1.5 blocks/CU =
// 4-6 waves/CU -- zero TLP, all load latency exposed. 64x64 doubles/triples blocks
// (proj 512 = 2/CU, qkv 768 = 3/CU even). Per-wave 16x64 out, 8 MFMA per BK-iter.
// Named prefetch regs only (R6 lesson: runtime-indexed local arrays -> scratch).
// LDS chunk-XOR swizzle: b128 frag reads land 8 lanes per 4-bank group = the
// balanced minimum for wave64 (1 KB / 256 B-per-clk = 4 clk, no extra conflict).
__device__ __forceinline__ void gemm_core64(const __bf16* __restrict__ A,
                                            const __bf16* __restrict__ B,
                                            int K,
                                            __bf16* AsB, __bf16* BsB,
                                            f32x4 (&acc)[4]) {
  const int tid = threadIdx.x;
  const int w = tid >> 6, l = tid & 63;
  const int quad = l >> 4, r16 = l & 15;
  const int srow = tid >> 2;        // 0..63 staging row (A and B)
  const int sc0  = (tid & 3) * 2;   // chunk pair base (8-elem chunks)
  const int wS0 = srow * 64 + ((sc0 ^ (srow & 7)) * 8);
  const int wS1 = srow * 64 + (((sc0 + 1) ^ (srow & 7)) * 8);
  const __bf16* gA = A + (size_t)srow * K + sc0 * 8;
  const __bf16* gB = B + (size_t)srow * K + sc0 * 8;
  int rA[2], rB[4][2];
#pragma unroll
  for (int ks = 0; ks < 2; ++ks) {
    int row = w * 16 + r16;
    rA[ks] = row * 64 + (((ks * 4 + quad) ^ (row & 7)) * 8);
  }
#pragma unroll
  for (int nt = 0; nt < 4; ++nt)
#pragma unroll
    for (int ks = 0; ks < 2; ++ks) {
      int row = nt * 16 + r16;
      rB[nt][ks] = row * 64 + (((ks * 4 + quad) ^ (row & 7)) * 8);
    }
  const int nIter = K >> 6;
  uint4 a0, a1, b0, b1;  // named regs only
  { const uint4* p = (const uint4*)gA; a0 = p[0]; a1 = p[1]; }
  { const uint4* p = (const uint4*)gB; b0 = p[0]; b1 = p[1]; }
  *(uint4*)(AsB + wS0) = a0; *(uint4*)(AsB + wS1) = a1;
  *(uint4*)(BsB + wS0) = b0; *(uint4*)(BsB + wS1) = b1;
  __syncthreads();
  int cur = 0;
  for (int it = 0; it < nIter; ++it) {
    if (it + 1 < nIter) {  // prefetch next K-slab (no wait here)
      const uint4* p = (const uint4*)(gA + ((it + 1) << 6));
      a0 = p[0]; a1 = p[1];
      const uint4* q = (const uint4*)(gB + ((it + 1) << 6));
      b0 = q[0]; b1 = q[1];
    }
    const __bf16* Asc = AsB + cur * 4096;
    const __bf16* Bsc = BsB + cur * 4096;
#pragma unroll
    for (int ks = 0; ks < 2; ++ks) {
      bf16x8 fa  = *(const bf16x8*)(Asc + rA[ks]);
      bf16x8 fb0 = *(const bf16x8*)(Bsc + rB[0][ks]);
      bf16x8 fb1 = *(const bf16x8*)(Bsc + rB[1][ks]);
      bf16x8 fb2 = *(const bf16x8*)(Bsc + rB[2][ks]);
      bf16x8 fb3 = *(const bf16x8*)(Bsc + rB[3][ks]);
      acc[0] = MFMA16(fa, fb0, acc[0]);
      acc[1] = MFMA16(fa, fb1, acc[1]);
      acc[2] = MFMA16(fa, fb2, acc[2]);
      acc[3] = MFMA16(fa, fb3, acc[3]);
    }
    if (it + 1 < nIter) {
      __builtin_amdgcn_sched_barrier(0);  // keep prefetch+MFMA above the waiting writes
      __bf16* Asn = AsB + (cur ^ 1) * 4096;
      __bf16* Bsn = BsB + (cur ^ 1) * 4096;
      *(uint4*)(Asn + wS0) = a0; *(uint4*)(Asn + wS1) = a1;
      *(uint4*)(Bsn + wS0) = b0; *(uint4*)(Bsn + wS1) = b1;
      __syncthreads();
      cur ^= 1;
    }
  }
}

// ---------------- QKV GEMM + fused norm+RoPE (Q,K) / V-transpose epilogue ----------
// grid (24, 32): n0 = bx*64 in [0,1536) (one head's 64 cols per block -> norm works),
// m0 = by*64. Epilogue math identical to R7 (proven numerics).
__global__ __launch_bounds__(256) void gemm_qkv_kernel(const __bf16* __restrict__ xb,
                                                       const __bf16* __restrict__ Wqkvb,
                                                       const float2* __restrict__ ropeT,
                                                       __bf16* __restrict__ Qb,
                                                       __bf16* __restrict__ Kb,
                                                       __bf16* __restrict__ Vt) {
  __shared__ __align__(16) __bf16 smem[16384];  // As 2x4096 | Bs 2x4096 (32 KB)
  __bf16* AsB = smem;
  __bf16* BsB = smem + 8192;
  f32x4 acc[4] = {};
  const int m0 = blockIdx.y * 64, n0 = blockIdx.x * 64;
  gemm_core64(xb + (size_t)m0 * C_DIM, Wqkvb + (size_t)n0 * C_DIM, C_DIM, AsB, BsB, acc);
  const int tid = threadIdx.x;
  const int w = tid >> 6, l = tid & 63, quad = l >> 4, r16 = l & 15;
  if (n0 < 1280) {  // Q or K: L2-norm + RoPE
    const bool isQ = n0 < 1024;
    const int head = isQ ? (n0 >> 6) : ((n0 - 1024) >> 6);
    __bf16* dstBase = (isQ ? Qb : Kb) + (size_t)head * T_SEQ * HD;
    const float osc = isQ ? 0.125f : 1.0f;  // fold 1/sqrt(d) into Q (2^-3 exact)
#pragma unroll
    for (int r = 0; r < 4; ++r) {
      float ss = acc[0][r] * acc[0][r] + acc[1][r] * acc[1][r] +
                 acc[2][r] * acc[2][r] + acc[3][r] * acc[3][r];
#pragma unroll
      for (int m = 1; m < 16; m <<= 1) ss += __shfl_xor(ss, m, 64);
      const float inv = osc / (sqrtf(ss) + 1e-6f);
      const int t = m0 + w * 16 + quad * 4 + r;
      const float2 cs0 = ropeT[t * 32 + r16];
      const float2 cs1 = ropeT[t * 32 + 16 + r16];
      const float v0 = acc[0][r] * inv, v1 = acc[1][r] * inv;
      const float v2 = acc[2][r] * inv, v3 = acc[3][r] * inv;
      __bf16* dst = dstBase + (size_t)t * HD;
      dst[r16]      = (__bf16)(v0 * cs0.x - v2 * cs0.y);
      dst[16 + r16] = (__bf16)(v1 * cs1.x - v3 * cs1.y);
      dst[32 + r16] = (__bf16)(v2 * cs0.x + v0 * cs0.y);
      dst[48 + r16] = (__bf16)(v3 * cs1.x + v1 * cs1.y);
    }
  } else {  // V: transpose to Vt[kvh][d][t] via reused LDS
    const int kvh = (n0 - 1280) >> 6;
    __syncthreads();  // all waves done reading As/Bs
    __bf16* Vs = smem;  // [64 d][stride 136] = 17.4 KB <= 32 KB
#pragma unroll
    for (int nt = 0; nt < 4; ++nt)
#pragma unroll
      for (int r = 0; r < 4; ++r)
        Vs[(nt * 16 + r16) * 136 + w * 16 + quad * 4 + r] = (__bf16)acc[nt][r];
    __syncthreads();
    const int d = tid >> 2, tc = (tid & 3) * 16;
    __bf16* dst = Vt + ((size_t)kvh * HD + d) * T_SEQ + m0 + tc;
    bf16x8 v0 = *(const bf16x8*)(Vs + d * 136 + tc);
    bf16x8 v1 = *(const bf16x8*)(Vs + d * 136 + tc + 8);
    *(bf16x8*)dst = v0;
    *(bf16x8*)(dst + 8) = v1;
  }
}

// ---------------- proj GEMM: grid (16, 32), f32 epilogue ----------------
__global__ __launch_bounds__(256) void gemm_proj_kernel(const __bf16* __restrict__ Yb,
                                                        const __bf16* __restrict__ Wpb,
                                                        float* __restrict__ C) {
  __shared__ __align__(16) __bf16 smem[16384];
  __bf16* AsB = smem;
  __bf16* BsB = smem + 8192;
  f32x4 acc[4] = {};
  const int m0 = blockIdx.y * 64, n0 = blockIdx.x * 64;
  gemm_core64(Yb + (size_t)m0 * C_DIM, Wpb + (size_t)n0 * C_DIM, C_DIM, AsB, BsB, acc);
  const int tid = threadIdx.x;
  const int w = tid >> 6, l = tid & 63, quad = l >> 4, r16 = l & 15;
  const int mrow = m0 + w * 16 + quad * 4;
  const int ncol = n0 + r16;
#pragma unroll
  for (int r = 0; r < 4; ++r) {
    size_t rowoff = (size_t)(mrow + r) * C_DIM;
    C[rowoff + ncol]      = acc[0][r];
    C[rowoff + ncol + 16] = acc[1][r];
    C[rowoff + ncol + 32] = acc[2][r];
    C[rowoff + ncol + 48] = acc[3][r];
  }
}

// ---------------- MFMA sliding-window attention, split-key blocks (R7, proven) ----------
// grid (T/32, NH) = 1024 blocks = 4/CU. Wave w: sub=w&1 = 16-query subtile,
// half=w>>1 = key-chunk half. Partials combined via LDS (valid without online-max:
// |s| <= 0.125). No register prefetch (R6: runtime-indexed arrays spill).
__global__ __launch_bounds__(256) void attn_mfma_kernel(const __bf16* __restrict__ Qb,
                                                        const __bf16* __restrict__ Kb,
                                                        const __bf16* __restrict__ Vt,
                                                        __bf16* __restrict__ Yb) {
  __shared__ __align__(16) __bf16 Pl[4][16][72];
  __shared__ __align__(16) float Oc[2][16][68];
  __shared__ float Ls[2][16];
  const int h = blockIdx.y, kvh = h >> 2;
  const int t0 = blockIdx.x * 32;
  const int tid = threadIdx.x;
  const int w = tid >> 6, l = tid & 63;
  const int quad = l >> 4, r16 = l & 15;
  const int sub = w & 1, half = w >> 1;
  const __bf16* qptr = Qb + ((size_t)h * T_SEQ + t0 + sub * 16 + r16) * HD + quad * 8;
  bf16x8 aq0 = *(const bf16x8*)(qptr);
  bf16x8 aq1 = *(const bf16x8*)(qptr + 32);
  const int keyStart = max(0, t0 - (WIN - 1)) & ~63;
  const int keyEnd = (t0 + 32 + 63) & ~63;
  const int nch = (keyEnd - keyStart) >> 6;   // <= 9
  const int nch2 = (nch + 1) >> 1;
  const int cbeg = half ? nch2 : 0;
  const int cend = half ? nch : nch2;
  const __bf16* kbase = Kb + (size_t)kvh * T_SEQ * HD;
  const __bf16* vbase = Vt + (size_t)kvh * HD * T_SEQ;
  const int tq_base = t0 + sub * 16 + quad * 4;
  f32x4 oacc[4] = {};
  float lsum[4] = {0.f, 0.f, 0.f, 0.f};
  for (int c = cbeg; c < cend; ++c) {
    const int key0 = keyStart + (c << 6);
    f32x4 s[4] = {};
#pragma unroll
    for (int nt = 0; nt < 4; ++nt) {
      const __bf16* kr = kbase + (size_t)(key0 + nt * 16 + r16) * HD + quad * 8;
      bf16x8 bk0 = *(const bf16x8*)kr;
      bf16x8 bk1 = *(const bf16x8*)(kr + 32);
      s[nt] = MFMA16(aq0, bk0, s[nt]);
      s[nt] = MFMA16(aq1, bk1, s[nt]);
    }
#pragma unroll
    for (int nt = 0; nt < 4; ++nt) {
      const int key = key0 + nt * 16 + r16;
#pragma unroll
      for (int r = 0; r < 4; ++r) {
        const int tq = tq_base + r;
        bool valid = (key <= tq) && (key > tq - WIN);
        float p = valid ? __expf(s[nt][r]) : 0.0f;
        lsum[r] += p;
        Pl[w][quad * 4 + r][nt * 16 + r16] = (__bf16)p;
      }
    }
    bf16x8 ap0 = *(const bf16x8*)(&Pl[w][r16][quad * 8]);
    bf16x8 ap1 = *(const bf16x8*)(&Pl[w][r16][32 + quad * 8]);
#pragma unroll
    for (int nt = 0; nt < 4; ++nt) {
      const __bf16* vr = vbase + (size_t)(nt * 16 + r16) * T_SEQ + key0 + quad * 8;
      bf16x8 bv0 = *(const bf16x8*)vr;
      bf16x8 bv1 = *(const bf16x8*)(vr + 32);
      oacc[nt] = MFMA16(ap0, bv0, oacc[nt]);
      oacc[nt] = MFMA16(ap1, bv1, oacc[nt]);
    }
  }
#pragma unroll
  for (int r = 0; r < 4; ++r) {
#pragma unroll
    for (int m = 1; m < 16; m <<= 1) lsum[r] += __shfl_xor(lsum[r], m, 64);
  }
  if (half == 1) {  // publish partials
#pragma unroll
    for (int nt = 0; nt < 4; ++nt)
#pragma unroll
      for (int r = 0; r < 4; ++r)
        Oc[sub][quad * 4 + r][nt * 16 + r16] = oacc[nt][r];
    if (r16 == 0) {
#pragma unroll
      for (int r = 0; r < 4; ++r) Ls[sub][quad * 4 + r] = lsum[r];
    }
  }
  __syncthreads();
  if (half == 0) {  // combine + normalize + store
#pragma unroll
    for (int r = 0; r < 4; ++r) {
      const float inv = 1.0f / (lsum[r] + Ls[sub][quad * 4 + r]);
      const size_t row = (size_t)(tq_base + r);
#pragma unroll
      for (int nt = 0; nt < 4; ++nt) {
        float o = oacc[nt][r] + Oc[sub][quad * 4 + r][nt * 16 + r16];
        Yb[row * C_DIM + h * HD + nt * 16 + r16] = (__bf16)(o * inv);
      }
    }
  }
}

extern "C" void kernel_launch(void* const* d_in, const int* in_sizes, int n_in,
                              void* d_out, int out_size, void* d_ws, size_t ws_size,
                              hipStream_t stream) {
  const float* x     = (const float*)d_in[0];
  const float* Wq    = (const float*)d_in[1];
  const float* Wkv   = (const float*)d_in[2];
  const float* Wproj = (const float*)d_in[3];
  float* out = (float*)d_out;

  __bf16* xb    = (__bf16*)d_ws;                         // [2048][1024]
  __bf16* Wqkvb = xb + (size_t)T_SEQ * C_DIM;            // [1536][1024]
  __bf16* Wpb   = Wqkvb + (size_t)1536 * C_DIM;          // [1024][1024]
  __bf16* Qb    = Wpb + (size_t)C_DIM * C_DIM;           // [16][2048][64]
  __bf16* Kb    = Qb + (size_t)NH * T_SEQ * HD;          // [4][2048][64]
  __bf16* Vt    = Kb + (size_t)NKV * T_SEQ * HD;         // [4][64][2048]
  __bf16* Yb    = Vt + (size_t)NKV * HD * T_SEQ;         // [2048][1024]
  float2* ropeT = (float2*)(Yb + (size_t)T_SEQ * C_DIM); // [2048][32]

  prep_kernel<<<4864, 256, 0, stream>>>(x, Wq, Wkv, Wproj, xb, Wqkvb, Wpb, ropeT);
  gemm_qkv_kernel<<<dim3(24, 32), 256, 0, stream>>>(xb, Wqkvb, ropeT, Qb, Kb, Vt);
  attn_mfma_kernel<<<dim3(T_SEQ / 32, NH), 256, 0, stream>>>(Qb, Kb, Vt, Yb);
  gemm_proj_kernel<<<dim3(16, 32), 256, 0, stream>>>(Yb, Wpb, out);
}